// Round 5
// baseline (255.448 us; speedup 1.0000x reference)
//
#include <hip/hip_runtime.h>

// LNCC, separable 5-tap Gaussian (sigma=1), fused single pass.
// (N=2, C=1, D=160, H=192, W=224) fp32 -> scalar.
// R10: R8 base (best: 117us; dbuf LDS, 1 barrier/iter, packed-fp32 v2f math)
//      + DCHUNK 20->32 (barrier intervals/output 1.3 -> 1.19, D-halo refetch
//      1.2x -> 1.125x, grid (7,12,10)=840 blocks) + loop peeling: 6-iter
//      warmup / branch-free steady loop (k=6..34, no per-iter predicates) /
//      3-iter epilogue. R9 lesson: +1 barrier/iter costs ~10us; occupancy
//      is NOT LDS-limited (19KB vs 37KB identical) -> spend LDS, save barriers.

#define NB 2
#define DD 160
#define HH 192
#define WW 224
#define SH 224
#define SD (224*192)
#define SN (224*192*160)

#define TW 32
#define TH 16
#define ROWS (TH+4)          // 20
#define DCHUNK 32
#define NCHUNK (DD/DCHUNK)   // 5

#define K0 0.05448868f
#define K1 0.24420134f
#define K2 0.40261995f

typedef float v2f __attribute__((ext_vector_type(2)));
typedef float v4f __attribute__((ext_vector_type(4)));

__global__ __launch_bounds__(640) void lncc_main(
    const float* __restrict__ A, const float* __restrict__ B,
    const float* __restrict__ M, double* __restrict__ acc)
{
    __shared__ v2f  sIJ[2][ROWS][36];   // raw (I,J) + W halo, dbuf
    __shared__ v4f  wbA[2][ROWS][32];   // (bI,bJ,bII,bJJ), dbuf
    __shared__ float wbC[2][ROWS][32];  // bIJ, dbuf
    __shared__ float redL[10], redM[10];

    const int wt = blockIdx.x;           // 0..6
    const int ht = blockIdx.y;           // 0..11
    const int zz = blockIdx.z;           // 0..9
    const int n  = (zz >= NCHUNK) ? 1 : 0;
    const int dc = zz - n * NCHUNK;      // 0..4
    const int w0 = wt * TW, h0 = ht * TH, d0 = dc * DCHUNK;

    const float* __restrict__ Ai = A + (size_t)n * SN;
    const float* __restrict__ Bi = B + (size_t)n * SN;
    const float* __restrict__ Mi = M + (size_t)n * SN;

    const int tid = threadIdx.x;
    const int r   = tid >> 5;            // 0..19
    const int c   = tid & 31;            // 0..31

    const int gh  = h0 + r - 2;
    const bool hv = (unsigned)gh < (unsigned)HH;
    const int ghc = hv ? gh : 0;
    const int hwm = ghc * SH + (w0 + c);          // 32-bit offsets
    const int gwl = w0 + c - 2, gwr = w0 + c + 2;
    const bool lv = hv && (c < 2)   && (gwl >= 0);
    const bool rv = hv && (c >= 30) && (gwr < WW);
    const bool anyh = lv || rv;
    const int hwh = ghc * SH + (lv ? gwl : (rv ? gwr : 0));
    const int mbase = (h0 + r) * SH + (w0 + c);
    const bool orow = (r < TH);          // wave-uniform (waves 8,9 false)

    // D-direction shift-register pipelines (oldest..newest)
    v2f pP0 = 0.f, pP1 = 0.f, pP2 = 0.f, pP3 = 0.f;   // (bI,bJ)
    v2f pQ0 = 0.f, pQ1 = 0.f, pQ2 = 0.f, pQ3 = 0.f;   // (bII,bJJ)
    float pC0 = 0.f, pC1 = 0.f, pC2 = 0.f, pC3 = 0.f; // bIJ
    float accL = 0.f, accM = 0.f;

    // prefetch registers for the slice staged at iteration k
    v2f nM = 0.f, nH = 0.f;

    // ---- stage helpers ----
    auto stage = [&](int pw) {
        sIJ[pw][r][c + 2] = nM;
        if (c < 2)        sIJ[pw][r][c]     = nH;
        else if (c >= 30) sIJ[pw][r][c + 4] = nH;
    };
    auto prefetch = [&](int dd, bool guard) {
        nM = 0.f; nH = 0.f;
        if (guard) {
            const int dof = dd * SD;
            if (hv)   { nM.x = Ai[dof + hwm]; nM.y = Bi[dof + hwm]; }
            if (anyh) { nH.x = Ai[dof + hwh]; nH.y = Bi[dof + hwh]; }
        }
    };
    auto wblur = [&](int px) {
        const v2f v0 = sIJ[px][r][c];
        const v2f v1 = sIJ[px][r][c + 1];
        const v2f v2 = sIJ[px][r][c + 2];
        const v2f v3 = sIJ[px][r][c + 3];
        const v2f v4 = sIJ[px][r][c + 4];
        const v2f b  = K0*(v0+v4) + K1*(v1+v3) + K2*v2;                     // (bI,bJ)
        const v2f bs = K0*(v0*v0+v4*v4) + K1*(v1*v1+v3*v3) + K2*(v2*v2);    // (bII,bJJ)
        const float bij = K0*(v0.x*v0.y+v4.x*v4.y) + K1*(v1.x*v1.y+v3.x*v3.y) + K2*(v2.x*v2.y);
        wbA[px][r][c] = (v4f){b.x, b.y, bs.x, bs.y};
        wbC[px][r][c] = bij;
    };
    auto hblur = [&](int pw, float mval, bool doout) {
        const v4f a0 = wbA[pw][r][c];
        const v4f a1 = wbA[pw][r + 1][c];
        const v4f a2 = wbA[pw][r + 2][c];
        const v4f a3 = wbA[pw][r + 3][c];
        const v4f a4 = wbA[pw][r + 4][c];
        const float c0 = wbC[pw][r][c];
        const float c1 = wbC[pw][r + 1][c];
        const float c2 = wbC[pw][r + 2][c];
        const float c3 = wbC[pw][r + 3][c];
        const float c4 = wbC[pw][r + 4][c];
        const v2f h1 = K0*(a0.xy+a4.xy) + K1*(a1.xy+a3.xy) + K2*a2.xy; // (hI,hJ)
        const v2f h2 = K0*(a0.zw+a4.zw) + K1*(a1.zw+a3.zw) + K2*a2.zw; // (hII,hJJ)
        const float hc = K0*(c0+c4) + K1*(c1+c3) + K2*c2;

        if (doout) {
            const v2f bP = K0*(pP0+h1) + K1*(pP1+pP3) + K2*pP2;   // (bI,bJ)
            const v2f bS = K0*(pQ0+h2) + K1*(pQ1+pQ3) + K2*pQ2;   // (bII,bJJ)
            const float bC = K0*(pC0+hc) + K1*(pC1+pC3) + K2*pC2; // bIJ
            const float cross = bC - bP.x * bP.y;
            const float vI = fmaxf(bS.x - bP.x * bP.x, 0.f) + 1e-5f;
            const float vJ = fmaxf(bS.y - bP.y * bP.y, 0.f) + 1e-5f;
            const float lncc = 1.0f - cross * rsqrtf(vI * vJ);
            accL += lncc * mval;
            accM += mval;
        }

        pP0 = pP1; pP1 = pP2; pP2 = pP3; pP3 = h1;
        pQ0 = pQ1; pQ1 = pQ2; pQ2 = pQ3; pQ3 = h2;
        pC0 = pC1; pC1 = pC2; pC2 = pC3; pC3 = hc;
    };

    // ---- initial prefetch: slice d0-2 (negative only for dc==0) ----
    {
        const int dd = d0 - 2;
        prefetch(dd, dd >= 0);
    }

    // ---- warmup: k = 0..5 (predicated, no outputs) ----
    for (int k = 0; k < 6; ++k) {
        const int pw = k & 1, px = pw ^ 1;
        stage(pw);
        const int dd = d0 - 1 + k;
        prefetch(dd, dd >= 0);            // dd < DD always here (<= d0+4)
        if (k >= 1) wblur(px);
        if (k >= 2 && orow) hblur(pw, 0.f, false);
        __syncthreads();
    }

    // ---- steady: k = 6..34 (29 iters, branch-free body) ----
#pragma unroll 2
    for (int k = 6; k < DCHUNK + 3; ++k) {
        const int pw = k & 1, px = pw ^ 1;
        stage(pw);
        const int dd = d0 - 1 + k;
        prefetch(dd, dd < DD);            // uniform guard; only dc==4 tail trips
        float mval = 0.f;
        if (orow) mval = Mi[(d0 - 6 + k) * SD + mbase];
        wblur(px);
        if (orow) hblur(pw, mval, true);
        __syncthreads();
    }

    // ---- epilogue: k = 35, 36, 37 ----
    {   // k = 35: stage last slice, no prefetch
        stage(1);
        float mval = 0.f;
        if (orow) mval = Mi[(d0 + DCHUNK - 3) * SD + mbase];
        wblur(0);
        if (orow) hblur(1, mval, true);
        __syncthreads();
    }
    {   // k = 36: last W-blur
        float mval = 0.f;
        if (orow) mval = Mi[(d0 + DCHUNK - 2) * SD + mbase];
        wblur(1);
        if (orow) hblur(0, mval, true);
        __syncthreads();
    }
    {   // k = 37: last H-blur + output
        float mval = 0.f;
        if (orow) {
            mval = Mi[(d0 + DCHUNK - 1) * SD + mbase];
            hblur(1, mval, true);
        }
    }

    // ---- reduction ----
#pragma unroll
    for (int off = 32; off > 0; off >>= 1) {
        accL += __shfl_down(accL, off, 64);
        accM += __shfl_down(accM, off, 64);
    }
    const int wave = tid >> 6;
    if ((tid & 63) == 0) { redL[wave] = accL; redM[wave] = accM; }
    __syncthreads();
    if (tid == 0) {
        float sL = 0.f, sM = 0.f;
#pragma unroll
        for (int kk = 0; kk < 10; ++kk) { sL += redL[kk]; sM += redM[kk]; }
        atomicAdd(&acc[0], (double)sL);
        atomicAdd(&acc[1], (double)sM);
    }
}

__global__ void lncc_final(const double* __restrict__ acc, float* __restrict__ out)
{
    out[0] = (float)(acc[0] / (acc[1] + 1e-8));
}

extern "C" void kernel_launch(void* const* d_in, const int* in_sizes, int n_in,
                              void* d_out, int out_size, void* d_ws, size_t ws_size,
                              hipStream_t stream)
{
    const float* A = (const float*)d_in[0];
    const float* B = (const float*)d_in[1];
    const float* M = (const float*)d_in[2];
    double* acc = (double*)d_ws;

    hipMemsetAsync(d_ws, 0, 2 * sizeof(double), stream);

    dim3 grid(WW / TW, HH / TH, NB * NCHUNK);   // (7, 12, 10) = 840 blocks
    dim3 block(640);
    hipLaunchKernelGGL(lncc_main, grid, block, 0, stream, A, B, M, acc);
    hipLaunchKernelGGL(lncc_final, dim3(1), dim3(1), 0, stream, acc, (float*)d_out);
}

// Round 6
// 228.795 us; speedup vs baseline: 1.1165x; 1.1165x over previous
//
#include <hip/hip_runtime.h>

// LNCC, separable 5-tap Gaussian (sigma=1), fused single pass.
// (N=2, C=1, D=160, H=192, W=224) fp32 -> scalar.
// R11: R8 base (best: 117us; 1344 blocks, 640 thr, 32x16x20 tile, dbuf LDS,
//      packed-fp32 v2f math) + ONE change: loop barrier is raw
//      "s_waitcnt lgkmcnt(0); s_barrier" instead of __syncthreads().
//      __syncthreads drains vmcnt(0) too, forcing the global prefetch
//      (VGPR-private, consumed only next iter) to complete at EVERY barrier
//      -> ~900cyc HBM latency exposed per iter at ~1 block/CU. The barrier
//      only guards LDS, so lgkmcnt(0) alone is sufficient; the compiler
//      still emits the data-dependent vmcnt wait before the ds_write that
//      consumes the prefetch regs next iteration (full iter to hide HBM).
//      R10 lesson (reverted): grid 840 starved CUs; keep 1344 blocks.

#define NB 2
#define DD 160
#define HH 192
#define WW 224
#define SH 224
#define SD (224*192)
#define SN (224*192*160)

#define TW 32
#define TH 16
#define ROWS (TH+4)          // 20
#define DCHUNK 20
#define NCHUNK (DD/DCHUNK)   // 8

#define K0 0.05448868f
#define K1 0.24420134f
#define K2 0.40261995f

typedef float v2f __attribute__((ext_vector_type(2)));
typedef float v4f __attribute__((ext_vector_type(4)));

__global__ __launch_bounds__(640) void lncc_main(
    const float* __restrict__ A, const float* __restrict__ B,
    const float* __restrict__ M, double* __restrict__ acc)
{
    __shared__ v2f  sIJ[2][ROWS][36];   // raw (I,J) + W halo, dbuf
    __shared__ v4f  wbA[2][ROWS][32];   // (bI,bJ,bII,bJJ), dbuf
    __shared__ float wbC[2][ROWS][32];  // bIJ, dbuf
    __shared__ float redL[10], redM[10];

    const int wt = blockIdx.x;           // 0..6
    const int ht = blockIdx.y;           // 0..11
    const int zz = blockIdx.z;           // 0..15
    const int n  = zz >> 3;
    const int dc = zz & 7;
    const int w0 = wt * TW, h0 = ht * TH, d0 = dc * DCHUNK;

    const float* __restrict__ Ai = A + (size_t)n * SN;
    const float* __restrict__ Bi = B + (size_t)n * SN;
    const float* __restrict__ Mi = M + (size_t)n * SN;

    const int tid = threadIdx.x;
    const int r   = tid >> 5;            // 0..19
    const int c   = tid & 31;            // 0..31

    const int gh  = h0 + r - 2;
    const bool hv = (unsigned)gh < (unsigned)HH;
    const int ghc = hv ? gh : 0;
    const int hwm = ghc * SH + (w0 + c);          // 32-bit offsets
    const int gwl = w0 + c - 2, gwr = w0 + c + 2;
    const bool lv = hv && (c < 2)   && (gwl >= 0);
    const bool rv = hv && (c >= 30) && (gwr < WW);
    const bool anyh = lv || rv;
    const int hwh = ghc * SH + (lv ? gwl : (rv ? gwr : 0));
    const int mbase = (h0 + r) * SH + (w0 + c);

    // D-direction shift-register pipelines (oldest..newest)
    v2f pP0 = 0.f, pP1 = 0.f, pP2 = 0.f, pP3 = 0.f;   // (bI,bJ)
    v2f pQ0 = 0.f, pQ1 = 0.f, pQ2 = 0.f, pQ3 = 0.f;   // (bII,bJJ)
    float pC0 = 0.f, pC1 = 0.f, pC2 = 0.f, pC3 = 0.f; // bIJ
    float accL = 0.f, accM = 0.f;

    // prefetch registers for the slice staged at iteration k
    v2f nM = 0.f, nH = 0.f;
    {
        const int dd = d0 - 2;
        if (dd >= 0) {
            const int dof = dd * SD;
            if (hv)   { nM.x = Ai[dof + hwm]; nM.y = Bi[dof + hwm]; }
            if (anyh) { nH.x = Ai[dof + hwh]; nH.y = Bi[dof + hwh]; }
        }
    }

    const int NIT = DCHUNK + 6;          // 26
#pragma unroll 2
    for (int k = 0; k < NIT; ++k) {
        const int pw = k & 1;            // parity staged THIS iter
        const int px = pw ^ 1;

        // ---- W: stage prefetched raw slice (slices d0-2 .. d0+DCHUNK+1) ----
        if (k < DCHUNK + 4) {
            sIJ[pw][r][c + 2] = nM;
            if (c < 2)        sIJ[pw][r][c]     = nH;
            else if (c >= 30) sIJ[pw][r][c + 4] = nH;
        }

        // ---- prefetch slice k+1 ----
        nM = 0.f; nH = 0.f;
        {
            const int dd = d0 - 1 + k;
            if ((k + 1 < DCHUNK + 4) && (dd >= 0) && (dd < DD)) {
                const int dof = dd * SD;
                if (hv)   { nM.x = Ai[dof + hwm]; nM.y = Bi[dof + hwm]; }
                if (anyh) { nH.x = Ai[dof + hwh]; nH.y = Bi[dof + hwh]; }
            }
        }
        // ---- this iteration's mask value ----
        const int  dout = d0 - 6 + k;
        const bool outv = (k >= 6) && (r < TH);
        float mval = 0.f;
        if (outv) mval = Mi[dout * SD + mbase];

        // ---- X: W-blur of slice staged last iteration (packed I/J) ----
        if (k >= 1 && k <= DCHUNK + 4) {
            const v2f v0 = sIJ[px][r][c];
            const v2f v1 = sIJ[px][r][c + 1];
            const v2f v2 = sIJ[px][r][c + 2];
            const v2f v3 = sIJ[px][r][c + 3];
            const v2f v4 = sIJ[px][r][c + 4];
            const v2f b  = K0*(v0+v4) + K1*(v1+v3) + K2*v2;           // (bI,bJ)
            const v2f bs = K0*(v0*v0+v4*v4) + K1*(v1*v1+v3*v3) + K2*(v2*v2); // (bII,bJJ)
            const float bij = K0*(v0.x*v0.y+v4.x*v4.y) + K1*(v1.x*v1.y+v3.x*v3.y) + K2*(v2.x*v2.y);
            wbA[px][r][c] = (v4f){b.x, b.y, bs.x, bs.y};
            wbC[px][r][c] = bij;
        }

        // ---- Y: H-blur of slice staged two iters ago + D-pipeline ----
        if (k >= 2 && r < TH) {
            const v4f a0 = wbA[pw][r][c];
            const v4f a1 = wbA[pw][r + 1][c];
            const v4f a2 = wbA[pw][r + 2][c];
            const v4f a3 = wbA[pw][r + 3][c];
            const v4f a4 = wbA[pw][r + 4][c];
            const float c0 = wbC[pw][r][c];
            const float c1 = wbC[pw][r + 1][c];
            const float c2 = wbC[pw][r + 2][c];
            const float c3 = wbC[pw][r + 3][c];
            const float c4 = wbC[pw][r + 4][c];
            const v2f h1 = K0*(a0.xy+a4.xy) + K1*(a1.xy+a3.xy) + K2*a2.xy; // (hI,hJ)
            const v2f h2 = K0*(a0.zw+a4.zw) + K1*(a1.zw+a3.zw) + K2*a2.zw; // (hII,hJJ)
            const float hc = K0*(c0+c4) + K1*(c1+c3) + K2*c2;

            if (outv) {
                const v2f bP = K0*(pP0+h1) + K1*(pP1+pP3) + K2*pP2;   // (bI,bJ)
                const v2f bS = K0*(pQ0+h2) + K1*(pQ1+pQ3) + K2*pQ2;   // (bII,bJJ)
                const float bC = K0*(pC0+hc) + K1*(pC1+pC3) + K2*pC2; // bIJ
                const float cross = bC - bP.x * bP.y;
                const float vI = fmaxf(bS.x - bP.x * bP.x, 0.f) + 1e-5f;
                const float vJ = fmaxf(bS.y - bP.y * bP.y, 0.f) + 1e-5f;
                const float lncc = 1.0f - cross * rsqrtf(vI * vJ);
                accL += lncc * mval;
                accM += mval;
            }

            pP0 = pP1; pP1 = pP2; pP2 = pP3; pP3 = h1;
            pQ0 = pQ1; pQ1 = pQ2; pQ2 = pQ3; pQ3 = h2;
            pC0 = pC1; pC1 = pC2; pC2 = pC3; pC3 = hc;
        }

        // LDS-only barrier: drain LDS (lgkmcnt) but leave global prefetch
        // loads (vmcnt, VGPR-private) in flight across the barrier.
        asm volatile("s_waitcnt lgkmcnt(0)\n\ts_barrier" ::: "memory");
    }

    // ---- reduction ----
#pragma unroll
    for (int off = 32; off > 0; off >>= 1) {
        accL += __shfl_down(accL, off, 64);
        accM += __shfl_down(accM, off, 64);
    }
    const int wave = tid >> 6;
    if ((tid & 63) == 0) { redL[wave] = accL; redM[wave] = accM; }
    __syncthreads();
    if (tid == 0) {
        float sL = 0.f, sM = 0.f;
#pragma unroll
        for (int kk = 0; kk < 10; ++kk) { sL += redL[kk]; sM += redM[kk]; }
        atomicAdd(&acc[0], (double)sL);
        atomicAdd(&acc[1], (double)sM);
    }
}

__global__ void lncc_final(const double* __restrict__ acc, float* __restrict__ out)
{
    out[0] = (float)(acc[0] / (acc[1] + 1e-8));
}

extern "C" void kernel_launch(void* const* d_in, const int* in_sizes, int n_in,
                              void* d_out, int out_size, void* d_ws, size_t ws_size,
                              hipStream_t stream)
{
    const float* A = (const float*)d_in[0];
    const float* B = (const float*)d_in[1];
    const float* M = (const float*)d_in[2];
    double* acc = (double*)d_ws;

    hipMemsetAsync(d_ws, 0, 2 * sizeof(double), stream);

    dim3 grid(WW / TW, HH / TH, NB * NCHUNK);   // (7, 12, 16) = 1344 blocks
    dim3 block(640);
    hipLaunchKernelGGL(lncc_main, grid, block, 0, stream, A, B, M, acc);
    hipLaunchKernelGGL(lncc_final, dim3(1), dim3(1), 0, stream, acc, (float*)d_out);
}